// Round 15
// baseline (368.262 us; speedup 1.0000x reference)
//
#include <hip/hip_runtime.h>

typedef float  f4     __attribute__((ext_vector_type(4)));
typedef short  short8 __attribute__((ext_vector_type(8)));

#define B_ 32
#define D_ 128
#define T_ 1024
#define K_ 4096
#define NROWS (B_ * T_)   // 32768
#define LPX 132
#define INF_ 3.4e38f

#define SCHED_FENCE() __builtin_amdgcn_sched_barrier(0)

// numpy computes t = a*a elementwise, THEN pairwise-sums (no fma fusion).
__device__ __forceinline__ float opaquef(float x) { asm volatile("" : "+v"(x)); return x; }

// numpy pairwise_sum base case for n=128: 8 accumulators,
// ((r0+r1)+(r2+r3))+((r4+r5)+(r6+r7)). Bit-exact replica (r12-proven).
__device__ float np_sumsq128(const float* a) {
  float r[8];
#pragma unroll
  for (int j = 0; j < 8; ++j) r[j] = opaquef(a[j] * a[j]);
#pragma unroll
  for (int i = 8; i < 128; i += 8) {
#pragma unroll
    for (int j = 0; j < 8; ++j) r[j] = r[j] + opaquef(a[i + j] * a[i + j]);
  }
  return ((r[0] + r[1]) + (r[2] + r[3])) + ((r[4] + r[5]) + (r[6] + r[7]));
}

// round-to-nearest-even fp32 -> bf16 (deterministic, rel err <= 2^-9)
__device__ __forceinline__ short bf16_rne(float f) {
  unsigned u = __float_as_uint(f);
  unsigned r = (u + 0x7FFFu + ((u >> 16) & 1u)) >> 16;
  return (short)r;
}

__global__ void wsq_kernel(const float* __restrict__ W, float* __restrict__ wsq,
                           unsigned* __restrict__ maxwsq) {
  int k = blockIdx.x * blockDim.x + threadIdx.x;
  if (k < K_) {
    float s = np_sumsq128(W + (size_t)k * D_);
    wsq[k] = s;
    atomicMax(maxwsq, __float_as_uint(s));  // positive floats: uint order == float order
  }
}

// Wbf fragment layout for mfma_f32_16x16x32_bf16 B-operand:
// elem e = ((ct*4+kk)*64 + lane)*8 + j holds bf16(W[ct*16 + (lane&15)][kk*32 + (lane>>4)*8 + j])
__global__ void wbf_prep_kernel(const float* __restrict__ W, short* __restrict__ Wbf) {
  int e = blockIdx.x * 256 + threadIdx.x;   // 524288 total
  int j = e & 7, lane = (e >> 3) & 63, kk = (e >> 9) & 3, ct = e >> 11;
  int code = (ct << 4) + (lane & 15);
  int k = (kk << 5) + (((lane >> 4) & 3) << 3) + j;
  Wbf[e] = bf16_rne(W[(size_t)code * D_ + k]);
}

// B-fragment load: linear byte pointer + imm offsets (r14-proven)
#define LDB(R0, R1, R2, R3, WQ)               \
  R0 = *(const short8*)(pwb);                 \
  R1 = *(const short8*)(pwb + 1024);          \
  R2 = *(const short8*)(pwb + 2048);          \
  R3 = *(const short8*)(pwb + 3072);          \
  WQ = *pwq;                                  \
  pwb += 4096; pwq += 16;

// Single-sweep consume: 8 MFMAs (same split-chain structure as r12-r14, so the
// WIN accumulation-order term is unchanged), then per-slot top-3 tracking via
// v_med3. Invariant m1<=m2<=m3; i1/i2 are the indices of m1/m2.
#define CONSUME_MIN(B0, B1, B2, B3, WQ, CT)                                    \
  do {                                                                         \
    f4 z = {0.f, 0.f, 0.f, 0.f};                                               \
    f4 A0 = __builtin_amdgcn_mfma_f32_16x16x32_bf16(afr0[0], B0, z, 0, 0, 0);  \
    A0 = __builtin_amdgcn_mfma_f32_16x16x32_bf16(afr0[1], B1, A0, 0, 0, 0);    \
    f4 A1 = __builtin_amdgcn_mfma_f32_16x16x32_bf16(afr0[2], B2, z, 0, 0, 0);  \
    A1 = __builtin_amdgcn_mfma_f32_16x16x32_bf16(afr0[3], B3, A1, 0, 0, 0);    \
    f4 C0 = __builtin_amdgcn_mfma_f32_16x16x32_bf16(afr1[0], B0, z, 0, 0, 0);  \
    C0 = __builtin_amdgcn_mfma_f32_16x16x32_bf16(afr1[1], B1, C0, 0, 0, 0);    \
    f4 C1 = __builtin_amdgcn_mfma_f32_16x16x32_bf16(afr1[2], B2, z, 0, 0, 0);  \
    C1 = __builtin_amdgcn_mfma_f32_16x16x32_bf16(afr1[3], B3, C1, 0, 0, 0);    \
    const int kk_ = ((CT) << 4) + cidx;                                        \
    _Pragma("unroll")                                                          \
    for (int j = 0; j < 4; ++j) {                                              \
      float u0 = __fmaf_rn(-2.f, A0[j] + A1[j], WQ);                           \
      bool c1 = u0 < m1[0][j], c2 = u0 < m2[0][j];                             \
      m3[0][j] = __builtin_amdgcn_fmed3f(u0, m2[0][j], m3[0][j]);              \
      m2[0][j] = __builtin_amdgcn_fmed3f(u0, m1[0][j], m2[0][j]);              \
      i2[0][j] = c1 ? i1[0][j] : (c2 ? kk_ : i2[0][j]);                        \
      m1[0][j] = fminf(u0, m1[0][j]);                                          \
      i1[0][j] = c1 ? kk_ : i1[0][j];                                          \
      float u1 = __fmaf_rn(-2.f, C0[j] + C1[j], WQ);                           \
      bool d1 = u1 < m1[1][j], d2 = u1 < m2[1][j];                             \
      m3[1][j] = __builtin_amdgcn_fmed3f(u1, m2[1][j], m3[1][j]);              \
      m2[1][j] = __builtin_amdgcn_fmed3f(u1, m1[1][j], m2[1][j]);              \
      i2[1][j] = d1 ? i1[1][j] : (d2 ? kk_ : i2[1][j]);                        \
      m1[1][j] = fminf(u1, m1[1][j]);                                          \
      i1[1][j] = d1 ? kk_ : i1[1][j];                                          \
    }                                                                          \
  } while (0)

// Single-sweep MFMA filter. Block = 32 rows (2 tiles), 4 waves each covering a
// 64-ct quarter once. Per-lane top-3 -> window insert; m3-in-window sets a
// per-row flag (possible 4th-in-lane miss) -> exact full scan in rescore.
// WIN formula identical to r11-r14 (validated).
__global__ __launch_bounds__(256) void filter_kernel(
    const float* __restrict__ x, const short* __restrict__ Wbf,
    const float* __restrict__ wsq, const unsigned* __restrict__ maxwsq,
    float* __restrict__ xsq_g, int* __restrict__ cnt, int* __restrict__ cand,
    int* __restrict__ flags) {
  __shared__ float xs[32][LPX];
  __shared__ float xsqs[32];
  __shared__ float umin_sh[32][4];
  const int tid = threadIdx.x;
  const int blkrow = blockIdx.x * 32;
  const int b = blockIdx.x >> 5, t0 = (blockIdx.x & 31) << 5;

  {  // stage x rows (coalesced along t)
    int tt = tid & 31, d0 = (tid >> 5) * 16;
    for (int dd = 0; dd < 16; ++dd) {
      int d = d0 + dd;
      xs[tt][d] = x[((size_t)b * D_ + d) * T_ + t0 + tt];
    }
  }
  __syncthreads();
  if (tid < 32) {
    float s = np_sumsq128(&xs[tid][0]);
    xsqs[tid] = s;
    xsq_g[blkrow + tid] = s;
  }
  __syncthreads();

  const int w = tid >> 6, lane = tid & 63;
  const int cidx = lane & 15;         // code within ct tile
  const int q = lane >> 4;            // k-slice / C-row group

  // A fragments for both row-tiles: lane holds row t*16+(lane&15), k = kk*32+q*8+j
  short8 afr0[4], afr1[4];
#pragma unroll
  for (int kk = 0; kk < 4; ++kk)
#pragma unroll
    for (int j = 0; j < 8; ++j) {
      int k = (kk << 5) + (q << 3) + j;
      afr0[kk][j] = bf16_rne(xs[cidx][k]);
      afr1[kk][j] = bf16_rne(xs[16 + cidx][k]);
    }

  const float mw = sqrtf(__uint_as_float(*maxwsq)) * 1.0001f;

  float m1[2][4], m2[2][4], m3[2][4];
  int   i1[2][4], i2[2][4];
#pragma unroll
  for (int t = 0; t < 2; ++t)
#pragma unroll
    for (int j = 0; j < 4; ++j) {
      m1[t][j] = INF_; m2[t][j] = INF_; m3[t][j] = INF_;
      i1[t][j] = 0x7fffffff; i2[t][j] = 0x7fffffff;
    }
  const int ct0 = w << 6;             // this wave's 64-ct quarter

  {
    const char*  pwb = (const char*)Wbf + (size_t)ct0 * 4096 + (size_t)lane * 16;
    const float* pwq = wsq + (ct0 << 4) + cidx;
    short8 p0, p1, p2, p3, n0, n1, n2, n3;
    float wqc, wqn;
    LDB(p0, p1, p2, p3, wqc)          // ct0
    for (int s = 0; s < 32; ++s) {
      const int c = ct0 + s * 2;
      LDB(n0, n1, n2, n3, wqn)        // ct0+2s+1
      SCHED_FENCE();
      CONSUME_MIN(p0, p1, p2, p3, wqc, c);
      SCHED_FENCE();
      LDB(p0, p1, p2, p3, wqc)        // ct0+2s+2 (last iter overreads mapped slack)
      SCHED_FENCE();
      CONSUME_MIN(n0, n1, n2, n3, wqn, c + 1);
      SCHED_FENCE();
    }
  }

  // min over the 16 code-lanes (butterfly) -> per-row quarter-min (same as r14)
  float lim[2][4];
#pragma unroll
  for (int t = 0; t < 2; ++t)
#pragma unroll
    for (int j = 0; j < 4; ++j) {
      float m = m1[t][j];
#pragma unroll
      for (int mask = 1; mask < 16; mask <<= 1)
        m = fminf(m, __shfl_xor(m, mask));
      if (cidx == 0) umin_sh[t * 16 + (q << 2) + j][w] = m;
    }
  __syncthreads();
  // merge quarters + window (same WIN formula as r11-r14)
#pragma unroll
  for (int t = 0; t < 2; ++t)
#pragma unroll
    for (int j = 0; j < 4; ++j) {
      int rl = t * 16 + (q << 2) + j;
      float mg = fminf(fminf(umin_sh[rl][0], umin_sh[rl][1]),
                       fminf(umin_sh[rl][2], umin_sh[rl][3]));
      float xn = sqrtf(xsqs[rl]) * 1.0001f;
      lim[t][j] = mg + 4.f * (0.0079f * xn * mw + 1e-5f) + 2.6e-5f;
    }

  // insertion: each lane contributes its top-2 if within window; m3 within
  // window => possible 4th-smallest miss in this lane => flag row (exact scan).
#pragma unroll
  for (int t = 0; t < 2; ++t)
#pragma unroll
    for (int j = 0; j < 4; ++j) {
      int row = blkrow + t * 16 + (q << 2) + j;
      if (m1[t][j] <= lim[t][j]) {
        int pos = atomicAdd(&cnt[row], 1);
        if (pos < 16) cand[(row << 4) + pos] = i1[t][j];
        else atomicOr(&flags[row], 1);
      }
      if (m2[t][j] <= lim[t][j]) {
        int pos = atomicAdd(&cnt[row], 1);
        if (pos < 16) cand[(row << 4) + pos] = i2[t][j];
        else atomicOr(&flags[row], 1);
      }
      if (m3[t][j] <= lim[t][j]) atomicOr(&flags[row], 1);
    }
}

// Exact rescore: lane c replays the bit-exact np fp32 pipeline for candidate c;
// lexicographic (v, k) min == np.argmin first-occurrence. Flagged rows take a
// fully-exact scan over all 4096 codes (insurance path, expected ~0 rows).
__global__ __launch_bounds__(256) void rescore_kernel(
    const float* __restrict__ x, const float* __restrict__ W,
    const float* __restrict__ wsq, const float* __restrict__ xsq,
    const int* __restrict__ cnt, const int* __restrict__ cand,
    const int* __restrict__ flags,
    int* __restrict__ qout, float* __restrict__ out2) {
  const int wid = threadIdx.x >> 6, lane = threadIdx.x & 63;
  const int r = blockIdx.x * 4 + wid;
  const float* xr = x + ((size_t)(r >> 10) * D_) * T_ + (r & 1023);
  int best;
  if (flags[r]) {
    // full exact scan: lane handles codes lane + 64*s (ascending within lane)
    float v = INF_; int kb = 0x7fffffff;
    for (int s = 0; s < K_ / 64; ++s) {
      int k = s * 64 + lane;
      const float* wr = W + (size_t)k * D_;
      float mm = 0.f;
#pragma unroll 16
      for (int d = 0; d < D_; ++d)
        mm = __fmaf_rn(xr[(size_t)d * T_], wr[d], mm);
      float vv = __fadd_rn(__fmaf_rn(-2.f, mm, wsq[k]), xsq[r]);
      if (vv < v) { v = vv; kb = k; }
    }
#pragma unroll
    for (int mask = 1; mask < 64; mask <<= 1) {
      float vo = __shfl_xor(v, mask); int ko = __shfl_xor(kb, mask);
      if (vo < v || (vo == v && ko < kb)) { v = vo; kb = ko; }
    }
    best = kb & (K_ - 1);
  } else {
    int c = cnt[r]; if (c > 16) c = 16;
    if (c == 1) {
      best = cand[r << 4] & (K_ - 1);
    } else {
      float v = INF_; int k = 0x7fffffff;
      if (lane < c) {
        k = cand[(r << 4) + lane] & (K_ - 1);
        const float* wr = W + (size_t)k * D_;
        float mm = 0.f;
#pragma unroll 16
        for (int d = 0; d < D_; ++d)
          mm = __fmaf_rn(xr[(size_t)d * T_], wr[d], mm);   // ascending-d sgemm chain
        v = __fadd_rn(__fmaf_rn(-2.f, mm, wsq[k]), xsq[r]);  // RN(wq-2mm) then +xsq
      }
#pragma unroll
      for (int mask = 1; mask < 16; mask <<= 1) {
        float vo = __shfl_xor(v, mask); int ko = __shfl_xor(k, mask);
        if (vo < v || (vo == v && ko < k)) { v = vo; k = ko; }
      }
      best = k & (K_ - 1);
    }
  }
  if (lane == 0) { qout[r] = best; out2[r] = (float)best; }
}

// out0[r, d] = W[q[r], d]  — coalesced along d
__global__ void scatter0_kernel(const float* __restrict__ W,
                                const int* __restrict__ q,
                                float* __restrict__ out0) {
  int r = blockIdx.x * 2 + (threadIdx.x >> 7);
  int d = threadIdx.x & 127;
  int k = q[r] & (K_ - 1);
  out0[(size_t)r * D_ + d] = W[(size_t)k * D_ + d];
}

// out1[b, d, t] = W[q[b,t], d]  — coalesced along t
__global__ void scatter1_kernel(const float* __restrict__ W,
                                const int* __restrict__ q,
                                float* __restrict__ out1) {
  int b = blockIdx.x >> 7;
  int d = blockIdx.x & 127;
  for (int t = threadIdx.x; t < T_; t += 256) {
    int k = q[b * T_ + t] & (K_ - 1);
    out1[((size_t)b * D_ + d) * T_ + t] = W[(size_t)k * D_ + d];
  }
}

extern "C" void kernel_launch(void* const* d_in, const int* in_sizes, int n_in,
                              void* d_out, int out_size, void* d_ws, size_t ws_size,
                              hipStream_t stream) {
  const float* x = (const float*)d_in[0];
  const float* W = (const float*)d_in[1];
  float* out  = (float*)d_out;
  float* out0 = out;                           // [B,T,D]  4194304
  float* out1 = out + (size_t)NROWS * D_;      // [B,D,T]  4194304
  float* out2 = out + 2 * (size_t)NROWS * D_;  // [B,T]    32768 (as float)

  // small scratch in ws (r9/r10 proved >=656 KB usable)
  float*    wsq   = (float*)d_ws;                               // 16 KB
  float*    xsq   = (float*)((char*)d_ws + (16 << 10));         // 128 KB
  int*      q     = (int*)((char*)d_ws + (144 << 10));          // 128 KB
  int*      cnt   = (int*)((char*)d_ws + (272 << 10));          // 128 KB
  unsigned* maxw  = (unsigned*)((char*)d_ws + (400 << 10));     // 4 B (pad to 4K)
  int*      flags = (int*)((char*)d_ws + (404 << 10));          // 128 KB

  // big scratch in out0 (read before scatter0 overwrites it; stream-ordered)
  int*   cand = (int*)out0;                          // 32768*16*4 = 2 MB
  short* Wbf  = (short*)((char*)(void*)out0 + (2 << 20));  // 1 MB

  // zero cnt + maxw + flags in one memset (272K .. 532K)
  hipMemsetAsync((char*)d_ws + (272 << 10), 0, (260 << 10) + 64, stream);
  wsq_kernel<<<K_ / 256, 256, 0, stream>>>(W, wsq, maxw);
  wbf_prep_kernel<<<K_ * D_ / 256, 256, 0, stream>>>(W, Wbf);
  filter_kernel<<<NROWS / 32, 256, 0, stream>>>(x, Wbf, wsq, maxw, xsq, cnt, cand, flags);
  rescore_kernel<<<NROWS / 4, 256, 0, stream>>>(x, W, wsq, xsq, cnt, cand, flags, q, out2);
  scatter0_kernel<<<NROWS / 2, 256, 0, stream>>>(W, q, out0);
  scatter1_kernel<<<B_ * D_, 256, 0, stream>>>(W, q, out1);
}

// Round 16
// 217.556 us; speedup vs baseline: 1.6927x; 1.6927x over previous
//
#include <hip/hip_runtime.h>

typedef float  f4     __attribute__((ext_vector_type(4)));
typedef float  f2     __attribute__((ext_vector_type(2)));
typedef short  short8 __attribute__((ext_vector_type(8)));

#define B_ 32
#define D_ 128
#define T_ 1024
#define K_ 4096
#define NROWS (B_ * T_)   // 32768
#define LPX 132
#define INF_ 3.4e38f

#define SCHED_FENCE() __builtin_amdgcn_sched_barrier(0)

// numpy computes t = a*a elementwise, THEN pairwise-sums (no fma fusion).
__device__ __forceinline__ float opaquef(float x) { asm volatile("" : "+v"(x)); return x; }

// numpy pairwise_sum base case for n=128: 8 accumulators,
// ((r0+r1)+(r2+r3))+((r4+r5)+(r6+r7)). Bit-exact replica (r12-proven).
__device__ float np_sumsq128(const float* a) {
  float r[8];
#pragma unroll
  for (int j = 0; j < 8; ++j) r[j] = opaquef(a[j] * a[j]);
#pragma unroll
  for (int i = 8; i < 128; i += 8) {
#pragma unroll
    for (int j = 0; j < 8; ++j) r[j] = r[j] + opaquef(a[i + j] * a[i + j]);
  }
  return ((r[0] + r[1]) + (r[2] + r[3])) + ((r[4] + r[5]) + (r[6] + r[7]));
}

// round-to-nearest-even fp32 -> bf16 (deterministic, rel err <= 2^-9)
__device__ __forceinline__ short bf16_rne(float f) {
  unsigned u = __float_as_uint(f);
  unsigned r = (u + 0x7FFFu + ((u >> 16) & 1u)) >> 16;
  return (short)r;
}

__global__ void wsq_kernel(const float* __restrict__ W, float* __restrict__ wsq,
                           unsigned* __restrict__ maxwsq) {
  int k = blockIdx.x * blockDim.x + threadIdx.x;
  if (k < K_) {
    float s = np_sumsq128(W + (size_t)k * D_);
    wsq[k] = s;
    atomicMax(maxwsq, __float_as_uint(s));  // positive floats: uint order == float order
  }
}

// Wbf fragment layout for mfma_f32_16x16x32_bf16 B-operand:
// elem e = ((ct*4+kk)*64 + lane)*8 + j holds bf16(W[ct*16 + (lane&15)][kk*32 + (lane>>4)*8 + j])
__global__ void wbf_prep_kernel(const float* __restrict__ W, short* __restrict__ Wbf) {
  int e = blockIdx.x * 256 + threadIdx.x;   // 524288 total
  int j = e & 7, lane = (e >> 3) & 63, kk = (e >> 9) & 3, ct = e >> 11;
  int code = (ct << 4) + (lane & 15);
  int k = (kk << 5) + (((lane >> 4) & 3) << 3) + j;
  Wbf[e] = bf16_rne(W[(size_t)code * D_ + k]);
}

// B-fragment load: linear byte pointer + imm offsets (r14-proven)
#define LDB(R0, R1, R2, R3, WQ)               \
  R0 = *(const short8*)(pwb);                 \
  R1 = *(const short8*)(pwb + 1024);          \
  R2 = *(const short8*)(pwb + 2048);          \
  R3 = *(const short8*)(pwb + 3072);          \
  WQ = *pwq;                                  \
  pwb += 4096; pwq += 16;

// top-4 tracker update for one u (invariant m1<=m2<=m3<=m4; i1..i3 match m1..m3)
#define TOP4_UPD(T, J, U, KK)                                                  \
  do {                                                                         \
    bool c1 = (U) < m1[T][J], c2 = (U) < m2[T][J], c3 = (U) < m3[T][J];        \
    m4[T][J] = __builtin_amdgcn_fmed3f((U), m3[T][J], m4[T][J]);               \
    m3[T][J] = __builtin_amdgcn_fmed3f((U), m2[T][J], m3[T][J]);               \
    m2[T][J] = __builtin_amdgcn_fmed3f((U), m1[T][J], m2[T][J]);               \
    m1[T][J] = fminf((U), m1[T][J]);                                           \
    i3[T][J] = c2 ? i2[T][J] : (c3 ? (KK) : i3[T][J]);                         \
    i2[T][J] = c1 ? i1[T][J] : (c2 ? (KK) : i2[T][J]);                         \
    i1[T][J] = c1 ? (KK) : i1[T][J];                                           \
  } while (0)

// Single-sweep consume: 8 MFMAs (same split-chain structure as r12-r15, so the
// WIN accumulation-order term is unchanged), then per-slot top-4 tracking.
#define CONSUME_MIN(B0, B1, B2, B3, WQ, CT)                                    \
  do {                                                                         \
    f4 z = {0.f, 0.f, 0.f, 0.f};                                               \
    f4 A0 = __builtin_amdgcn_mfma_f32_16x16x32_bf16(afr0[0], B0, z, 0, 0, 0);  \
    A0 = __builtin_amdgcn_mfma_f32_16x16x32_bf16(afr0[1], B1, A0, 0, 0, 0);    \
    f4 A1 = __builtin_amdgcn_mfma_f32_16x16x32_bf16(afr0[2], B2, z, 0, 0, 0);  \
    A1 = __builtin_amdgcn_mfma_f32_16x16x32_bf16(afr0[3], B3, A1, 0, 0, 0);    \
    f4 C0 = __builtin_amdgcn_mfma_f32_16x16x32_bf16(afr1[0], B0, z, 0, 0, 0);  \
    C0 = __builtin_amdgcn_mfma_f32_16x16x32_bf16(afr1[1], B1, C0, 0, 0, 0);    \
    f4 C1 = __builtin_amdgcn_mfma_f32_16x16x32_bf16(afr1[2], B2, z, 0, 0, 0);  \
    C1 = __builtin_amdgcn_mfma_f32_16x16x32_bf16(afr1[3], B3, C1, 0, 0, 0);    \
    const int kk_ = ((CT) << 4) + cidx;                                        \
    _Pragma("unroll")                                                          \
    for (int j = 0; j < 4; ++j) {                                              \
      float u0 = __fmaf_rn(-2.f, A0[j] + A1[j], WQ);                           \
      TOP4_UPD(0, j, u0, kk_);                                                 \
      float u1 = __fmaf_rn(-2.f, C0[j] + C1[j], WQ);                           \
      TOP4_UPD(1, j, u1, kk_);                                                 \
    }                                                                          \
  } while (0)

// Single-sweep MFMA filter. Block = 32 rows (2 tiles), 4 waves each covering a
// 64-ct quarter once. Per-lane top-3 inserted when within window; m4 within
// window => possible 4th-in-lane miss => flag row (exact LDS-staged scan).
// WIN formula identical to r11-r15 (validated).
__global__ __launch_bounds__(256) void filter_kernel(
    const float* __restrict__ x, const short* __restrict__ Wbf,
    const float* __restrict__ wsq, const unsigned* __restrict__ maxwsq,
    float* __restrict__ xsq_g, int* __restrict__ cnt, int* __restrict__ cand,
    int* __restrict__ flags, int* __restrict__ nflag, int* __restrict__ flist) {
  __shared__ float xs[32][LPX];
  __shared__ float xsqs[32];
  __shared__ float umin_sh[32][4];
  const int tid = threadIdx.x;
  const int blkrow = blockIdx.x * 32;
  const int b = blockIdx.x >> 5, t0 = (blockIdx.x & 31) << 5;

  {  // stage x rows (coalesced along t)
    int tt = tid & 31, d0 = (tid >> 5) * 16;
    for (int dd = 0; dd < 16; ++dd) {
      int d = d0 + dd;
      xs[tt][d] = x[((size_t)b * D_ + d) * T_ + t0 + tt];
    }
  }
  __syncthreads();
  if (tid < 32) {
    float s = np_sumsq128(&xs[tid][0]);
    xsqs[tid] = s;
    xsq_g[blkrow + tid] = s;
  }
  __syncthreads();

  const int w = tid >> 6, lane = tid & 63;
  const int cidx = lane & 15;         // code within ct tile
  const int q = lane >> 4;            // k-slice / C-row group

  // A fragments for both row-tiles: lane holds row t*16+(lane&15), k = kk*32+q*8+j
  short8 afr0[4], afr1[4];
#pragma unroll
  for (int kk = 0; kk < 4; ++kk)
#pragma unroll
    for (int j = 0; j < 8; ++j) {
      int k = (kk << 5) + (q << 3) + j;
      afr0[kk][j] = bf16_rne(xs[cidx][k]);
      afr1[kk][j] = bf16_rne(xs[16 + cidx][k]);
    }

  const float mw = sqrtf(__uint_as_float(*maxwsq)) * 1.0001f;

  float m1[2][4], m2[2][4], m3[2][4], m4[2][4];
  int   i1[2][4], i2[2][4], i3[2][4];
#pragma unroll
  for (int t = 0; t < 2; ++t)
#pragma unroll
    for (int j = 0; j < 4; ++j) {
      m1[t][j] = INF_; m2[t][j] = INF_; m3[t][j] = INF_; m4[t][j] = INF_;
      i1[t][j] = 0x7fffffff; i2[t][j] = 0x7fffffff; i3[t][j] = 0x7fffffff;
    }
  const int ct0 = w << 6;             // this wave's 64-ct quarter

  {
    const char*  pwb = (const char*)Wbf + (size_t)ct0 * 4096 + (size_t)lane * 16;
    const float* pwq = wsq + (ct0 << 4) + cidx;
    short8 p0, p1, p2, p3, n0, n1, n2, n3;
    float wqc, wqn;
    LDB(p0, p1, p2, p3, wqc)          // ct0
    for (int s = 0; s < 32; ++s) {
      const int c = ct0 + s * 2;
      LDB(n0, n1, n2, n3, wqn)        // ct0+2s+1
      SCHED_FENCE();
      CONSUME_MIN(p0, p1, p2, p3, wqc, c);
      SCHED_FENCE();
      LDB(p0, p1, p2, p3, wqc)        // ct0+2s+2 (last iter overreads mapped slack)
      SCHED_FENCE();
      CONSUME_MIN(n0, n1, n2, n3, wqn, c + 1);
      SCHED_FENCE();
    }
  }

  // min over the 16 code-lanes (butterfly) -> per-row quarter-min (same as r14)
  float lim[2][4];
#pragma unroll
  for (int t = 0; t < 2; ++t)
#pragma unroll
    for (int j = 0; j < 4; ++j) {
      float m = m1[t][j];
#pragma unroll
      for (int mask = 1; mask < 16; mask <<= 1)
        m = fminf(m, __shfl_xor(m, mask));
      if (cidx == 0) umin_sh[t * 16 + (q << 2) + j][w] = m;
    }
  __syncthreads();
  // merge quarters + window (same WIN formula as r11-r15)
#pragma unroll
  for (int t = 0; t < 2; ++t)
#pragma unroll
    for (int j = 0; j < 4; ++j) {
      int rl = t * 16 + (q << 2) + j;
      float mg = fminf(fminf(umin_sh[rl][0], umin_sh[rl][1]),
                       fminf(umin_sh[rl][2], umin_sh[rl][3]));
      float xn = sqrtf(xsqs[rl]) * 1.0001f;
      lim[t][j] = mg + 4.f * (0.0079f * xn * mw + 1e-5f) + 2.6e-5f;
    }

  // insertion: lane contributes top-3 if within window; m4 within window =>
  // possible 4th-smallest miss => flag row exactly-once into the list.
#pragma unroll
  for (int t = 0; t < 2; ++t)
#pragma unroll
    for (int j = 0; j < 4; ++j) {
      int row = blkrow + t * 16 + (q << 2) + j;
      bool ovf = false;
      if (m1[t][j] <= lim[t][j]) {
        int pos = atomicAdd(&cnt[row], 1);
        if (pos < 16) cand[(row << 4) + pos] = i1[t][j]; else ovf = true;
      }
      if (m2[t][j] <= lim[t][j]) {
        int pos = atomicAdd(&cnt[row], 1);
        if (pos < 16) cand[(row << 4) + pos] = i2[t][j]; else ovf = true;
      }
      if (m3[t][j] <= lim[t][j]) {
        int pos = atomicAdd(&cnt[row], 1);
        if (pos < 16) cand[(row << 4) + pos] = i3[t][j]; else ovf = true;
      }
      if (ovf || m4[t][j] <= lim[t][j]) {
        int old = atomicOr(&flags[row], 1);
        if (old == 0) { int p = atomicAdd(nflag, 1); flist[p] = row; }
      }
    }
}

// Exact rescore: lane c replays the bit-exact np fp32 pipeline for candidate c;
// lexicographic (v, k) min == np.argmin first-occurrence. Flagged rows are
// handled by exact_kernel.
__global__ __launch_bounds__(256) void rescore_kernel(
    const float* __restrict__ x, const float* __restrict__ W,
    const float* __restrict__ wsq, const float* __restrict__ xsq,
    const int* __restrict__ cnt, const int* __restrict__ cand,
    const int* __restrict__ flags,
    int* __restrict__ qout, float* __restrict__ out2) {
  const int wid = threadIdx.x >> 6, lane = threadIdx.x & 63;
  const int r = blockIdx.x * 4 + wid;
  if (flags[r]) return;   // exact_kernel owns this row
  int c = cnt[r]; if (c > 16) c = 16;
  int best;
  if (c == 1) {
    best = cand[r << 4] & (K_ - 1);
  } else {
    const float* xr = x + ((size_t)(r >> 10) * D_) * T_ + (r & 1023);
    float v = INF_; int k = 0x7fffffff;
    if (lane < c) {
      k = cand[(r << 4) + lane] & (K_ - 1);
      const float* wr = W + (size_t)k * D_;
      float mm = 0.f;
#pragma unroll 16
      for (int d = 0; d < D_; ++d)
        mm = __fmaf_rn(xr[(size_t)d * T_], wr[d], mm);   // ascending-d sgemm chain
      v = __fadd_rn(__fmaf_rn(-2.f, mm, wsq[k]), xsq[r]);  // RN(wq-2mm) then +xsq
    }
#pragma unroll
    for (int mask = 1; mask < 16; mask <<= 1) {
      float vo = __shfl_xor(v, mask); int ko = __shfl_xor(k, mask);
      if (vo < v || (vo == v && ko < k)) { v = vo; k = ko; }
    }
    best = k & (K_ - 1);
  }
  if (lane == 0) { qout[r] = best; out2[r] = (float)best; }
}

// Exact full-scan for flagged rows (insurance; expected ~0-1 rows). LDS-staged
// coalesced W reads; bit-exact np chain; lexicographic (v,k) min.
__global__ __launch_bounds__(256) void exact_kernel(
    const float* __restrict__ x, const float* __restrict__ W,
    const float* __restrict__ wsq, const float* __restrict__ xsq,
    const int* __restrict__ nflag, const int* __restrict__ flist,
    int* __restrict__ qout, float* __restrict__ out2) {
  __shared__ float xrow[128];
  __shared__ float wl[64][130];   // pad 130: 4-way bank alias on compute reads
  int n = *nflag;
  for (int fi = blockIdx.x; fi < n; fi += gridDim.x) {
    int r = flist[fi] & (NROWS - 1);
    const float* xr = x + ((size_t)(r >> 10) * D_) * T_ + (r & 1023);
    if (threadIdx.x < 128) xrow[threadIdx.x] = xr[(size_t)threadIdx.x * T_];
    float v = INF_; int kb = 0x7fffffff;
    for (int s = 0; s < K_ / 64; ++s) {
      __syncthreads();   // xrow ready / prev compute done
      const f2* src = (const f2*)(W + (size_t)s * 64 * D_);   // 64 rows contiguous
      for (int e = threadIdx.x; e < 4096; e += 256) {
        f2 val = src[e];
        *(f2*)&wl[e >> 6][(e & 63) * 2] = val;
      }
      __syncthreads();
      if (threadIdx.x < 64) {
        int k = s * 64 + threadIdx.x;
        float mm = 0.f;
#pragma unroll 16
        for (int d = 0; d < D_; ++d)
          mm = __fmaf_rn(xrow[d], wl[threadIdx.x][d], mm);   // ascending-d chain
        float vv = __fadd_rn(__fmaf_rn(-2.f, mm, wsq[k]), xsq[r]);
        if (vv < v) { v = vv; kb = k; }   // strict < ; k ascending per lane
      }
    }
    if (threadIdx.x < 64) {
#pragma unroll
      for (int mask = 1; mask < 64; mask <<= 1) {
        float vo = __shfl_xor(v, mask); int ko = __shfl_xor(kb, mask);
        if (vo < v || (vo == v && ko < kb)) { v = vo; kb = ko; }
      }
      if (threadIdx.x == 0) {
        int best = kb & (K_ - 1);
        qout[r] = best; out2[r] = (float)best;
      }
    }
    __syncthreads();   // protect xrow/wl before next fi
  }
}

// out0[r, d] = W[q[r], d]  — coalesced along d
__global__ void scatter0_kernel(const float* __restrict__ W,
                                const int* __restrict__ q,
                                float* __restrict__ out0) {
  int r = blockIdx.x * 2 + (threadIdx.x >> 7);
  int d = threadIdx.x & 127;
  int k = q[r] & (K_ - 1);
  out0[(size_t)r * D_ + d] = W[(size_t)k * D_ + d];
}

// out1[b, d, t] = W[q[b,t], d]  — coalesced along t
__global__ void scatter1_kernel(const float* __restrict__ W,
                                const int* __restrict__ q,
                                float* __restrict__ out1) {
  int b = blockIdx.x >> 7;
  int d = blockIdx.x & 127;
  for (int t = threadIdx.x; t < T_; t += 256) {
    int k = q[b * T_ + t] & (K_ - 1);
    out1[((size_t)b * D_ + d) * T_ + t] = W[(size_t)k * D_ + d];
  }
}

extern "C" void kernel_launch(void* const* d_in, const int* in_sizes, int n_in,
                              void* d_out, int out_size, void* d_ws, size_t ws_size,
                              hipStream_t stream) {
  const float* x = (const float*)d_in[0];
  const float* W = (const float*)d_in[1];
  float* out  = (float*)d_out;
  float* out0 = out;                           // [B,T,D]  4194304
  float* out1 = out + (size_t)NROWS * D_;      // [B,D,T]  4194304
  float* out2 = out + 2 * (size_t)NROWS * D_;  // [B,T]    32768 (as float)

  // small scratch in ws (532 KB, within the r14-proven envelope)
  float*    wsq   = (float*)d_ws;                               // 16 KB
  float*    xsq   = (float*)((char*)d_ws + (16 << 10));         // 128 KB
  int*      q     = (int*)((char*)d_ws + (144 << 10));          // 128 KB
  int*      cnt   = (int*)((char*)d_ws + (272 << 10));          // 128 KB
  unsigned* maxw  = (unsigned*)((char*)d_ws + (400 << 10));     // 4 B (4K pad)
  int*      flags = (int*)((char*)d_ws + (404 << 10));          // 128 KB

  // big scratch in out0 (read before scatter0 overwrites it; stream-ordered)
  int*   cand  = (int*)out0;                                // 2 MB
  short* Wbf   = (short*)((char*)(void*)out0 + (2 << 20));  // 1 MB
  int*   flist = (int*)((char*)(void*)out0 + (3 << 20));    // 128 KB
  int*   nflag = (int*)((char*)(void*)out0 + (3 << 20) + (128 << 10));  // 4 B

  // zero cnt + maxw + flags (272K..532K) and nflag
  hipMemsetAsync((char*)d_ws + (272 << 10), 0, (260 << 10) + 64, stream);
  hipMemsetAsync(nflag, 0, 64, stream);
  wsq_kernel<<<K_ / 256, 256, 0, stream>>>(W, wsq, maxw);
  wbf_prep_kernel<<<K_ * D_ / 256, 256, 0, stream>>>(W, Wbf);
  filter_kernel<<<NROWS / 32, 256, 0, stream>>>(x, Wbf, wsq, maxw, xsq, cnt, cand,
                                                flags, nflag, flist);
  rescore_kernel<<<NROWS / 4, 256, 0, stream>>>(x, W, wsq, xsq, cnt, cand, flags, q, out2);
  exact_kernel<<<64, 256, 0, stream>>>(x, W, wsq, xsq, nflag, flist, q, out2);
  scatter0_kernel<<<NROWS / 2, 256, 0, stream>>>(W, q, out0);
  scatter1_kernel<<<B_ * D_, 256, 0, stream>>>(W, q, out1);
}